// Round 3
// baseline (215.225 us; speedup 1.0000x reference)
//
#include <hip/hip_runtime.h>

// 2-qubit gate on qubits (5,12) of a 24-qubit f32 state with batch=4.
// Flat element index: 26 bits. Qubit-5 bit at position 20, qubit-12 bit at 13.
// In float4 units: bits 18 and 11.
// Pure streaming (zero reuse, 512 MiB traffic > 256 MiB L3) -> nontemporal
// loads/stores + 2 float4-groups per thread for deeper MLP.

typedef float f32x4 __attribute__((ext_vector_type(4)));  // native vector: nt-builtin ok

__global__ __launch_bounds__(256) void gate_q5_q12_kernel(
    const float* __restrict__ state,
    const float* __restrict__ mat,   // [4][4][1] row-major, 16 floats
    float* __restrict__ out) {

    float m[4][4];
#pragma unroll
    for (int i = 0; i < 4; ++i)
#pragma unroll
        for (int j = 0; j < 4; ++j)
            m[i][j] = mat[i * 4 + j];

    const unsigned S12 = 1u << 11;  // 2^13 elements / 4
    const unsigned S5  = 1u << 18;  // 2^20 elements / 4

    const f32x4* __restrict__ s4 = (const f32x4*)state;
    f32x4* __restrict__ o4 = (f32x4*)out;

    // 2^21 threads, each handling 2 consecutive float4-groups.
    const unsigned t = blockIdx.x * blockDim.x + threadIdx.x;  // [0, 2^21)

#pragma unroll
    for (int g = 0; g < 2; ++g) {
        const unsigned tt = (t << 1) | g;          // [0, 2^22)
        const unsigned low  = tt & 0x7FFu;         // bits 0-10
        const unsigned mid  = (tt >> 11) & 0x3Fu;  // -> bits 12-17
        const unsigned high = tt >> 17;            // -> bits 19-23
        const unsigned base4 = low | (mid << 12) | (high << 19);

        f32x4 v0 = __builtin_nontemporal_load(&s4[base4]);             // j=0
        f32x4 v1 = __builtin_nontemporal_load(&s4[base4 + S12]);       // j=1
        f32x4 v2 = __builtin_nontemporal_load(&s4[base4 + S5]);        // j=2
        f32x4 v3 = __builtin_nontemporal_load(&s4[base4 + S5 + S12]);  // j=3

        f32x4 r0 = m[0][0]*v0 + m[0][1]*v1 + m[0][2]*v2 + m[0][3]*v3;
        f32x4 r1 = m[1][0]*v0 + m[1][1]*v1 + m[1][2]*v2 + m[1][3]*v3;
        f32x4 r2 = m[2][0]*v0 + m[2][1]*v1 + m[2][2]*v2 + m[2][3]*v3;
        f32x4 r3 = m[3][0]*v0 + m[3][1]*v1 + m[3][2]*v2 + m[3][3]*v3;

        __builtin_nontemporal_store(r0, &o4[base4]);             // i=0
        __builtin_nontemporal_store(r1, &o4[base4 + S12]);       // i=1
        __builtin_nontemporal_store(r2, &o4[base4 + S5]);        // i=2
        __builtin_nontemporal_store(r3, &o4[base4 + S5 + S12]);  // i=3
    }
}

extern "C" void kernel_launch(void* const* d_in, const int* in_sizes, int n_in,
                              void* d_out, int out_size, void* d_ws, size_t ws_size,
                              hipStream_t stream) {
    const float* state = (const float*)d_in[0];  // 2^26 floats
    const float* mat   = (const float*)d_in[1];  // 16 floats
    float* out = (float*)d_out;

    const int nthreads = 1 << 21;   // 2 float4-groups per thread
    const int block = 256;
    gate_q5_q12_kernel<<<nthreads / block, block, 0, stream>>>(state, mat, out);
}

// Round 4
// 93.116 us; speedup vs baseline: 2.3114x; 2.3114x over previous
//
#include <hip/hip_runtime.h>

// 2-qubit gate on qubits (5,12) of a 24-qubit f32 state with batch=4.
// Flat element index: 26 bits. Qubit-5 bit at position 20, qubit-12 bit at 13.
// In float4 units: bits 18 and 11.
// Pure streaming (zero reuse, 512 MiB traffic > 256 MiB L3) -> nontemporal
// loads/stores. 2 groups/thread, GRID-STRIDED (tt = t and t + 2^21) so every
// instruction stays lane-contiguous (R3 lesson: interleaved (t<<1)|g broke
// coalescing -> 2x WRITE_SIZE).

typedef float f32x4 __attribute__((ext_vector_type(4)));  // native vector: nt-builtin ok

__global__ __launch_bounds__(256) void gate_q5_q12_kernel(
    const float* __restrict__ state,
    const float* __restrict__ mat,   // [4][4][1] row-major, 16 floats
    float* __restrict__ out) {

    float m[4][4];
#pragma unroll
    for (int i = 0; i < 4; ++i)
#pragma unroll
        for (int j = 0; j < 4; ++j)
            m[i][j] = mat[i * 4 + j];

    const unsigned S12 = 1u << 11;  // 2^13 elements / 4
    const unsigned S5  = 1u << 18;  // 2^20 elements / 4

    const f32x4* __restrict__ s4 = (const f32x4*)state;
    f32x4* __restrict__ o4 = (f32x4*)out;

    const unsigned t = blockIdx.x * blockDim.x + threadIdx.x;  // [0, 2^21)

#pragma unroll
    for (int g = 0; g < 2; ++g) {
        const unsigned tt = t + (g << 21);         // [0, 2^22), lane-contiguous
        const unsigned low  = tt & 0x7FFu;         // bits 0-10
        const unsigned mid  = (tt >> 11) & 0x3Fu;  // -> bits 12-17
        const unsigned high = tt >> 17;            // -> bits 19-23
        const unsigned base4 = low | (mid << 12) | (high << 19);

        f32x4 v0 = __builtin_nontemporal_load(&s4[base4]);             // j=0
        f32x4 v1 = __builtin_nontemporal_load(&s4[base4 + S12]);       // j=1
        f32x4 v2 = __builtin_nontemporal_load(&s4[base4 + S5]);        // j=2
        f32x4 v3 = __builtin_nontemporal_load(&s4[base4 + S5 + S12]);  // j=3

        f32x4 r0 = m[0][0]*v0 + m[0][1]*v1 + m[0][2]*v2 + m[0][3]*v3;
        f32x4 r1 = m[1][0]*v0 + m[1][1]*v1 + m[1][2]*v2 + m[1][3]*v3;
        f32x4 r2 = m[2][0]*v0 + m[2][1]*v1 + m[2][2]*v2 + m[2][3]*v3;
        f32x4 r3 = m[3][0]*v0 + m[3][1]*v1 + m[3][2]*v2 + m[3][3]*v3;

        __builtin_nontemporal_store(r0, &o4[base4]);             // i=0
        __builtin_nontemporal_store(r1, &o4[base4 + S12]);       // i=1
        __builtin_nontemporal_store(r2, &o4[base4 + S5]);        // i=2
        __builtin_nontemporal_store(r3, &o4[base4 + S5 + S12]);  // i=3
    }
}

extern "C" void kernel_launch(void* const* d_in, const int* in_sizes, int n_in,
                              void* d_out, int out_size, void* d_ws, size_t ws_size,
                              hipStream_t stream) {
    const float* state = (const float*)d_in[0];  // 2^26 floats
    const float* mat   = (const float*)d_in[1];  // 16 floats
    float* out = (float*)d_out;

    const int nthreads = 1 << 21;   // 2 grid-strided float4-groups per thread
    const int block = 256;
    gate_q5_q12_kernel<<<nthreads / block, block, 0, stream>>>(state, mat, out);
}